// Round 1
// baseline (1788.750 us; speedup 1.0000x reference)
//
#include <hip/hip_runtime.h>

typedef __attribute__((ext_vector_type(8))) short shortx8;
typedef __attribute__((ext_vector_type(4))) float floatx4;

constexpr int NAc = 4096;     // atoms
constexpr int NEc = 65536;    // edges
constexpr int NTc = 262144;   // triplets
constexpr float PI_F = 3.14159265358979323846f;
constexpr float SQ25 = 0.63245553203367587f;   // sqrt(2/5)

__device__ __forceinline__ float bf2f(unsigned short h){ return __uint_as_float(((unsigned)h)<<16); }
__device__ __forceinline__ unsigned short f2bf(float f){
  unsigned u = __float_as_uint(f);
  u += 0x7fffu + ((u>>16)&1u);
  return (unsigned short)(u>>16);
}
__device__ __forceinline__ float swishf(float x){ return x/(1.f+__expf(-x)); }

__device__ __forceinline__ floatx4 mfma16x16x32bf(shortx8 a, shortx8 b, floatx4 c){
  floatx4 d;
  asm("v_mfma_f32_16x16x32_bf16 %0, %1, %2, %3" : "=v"(d) : "v"(a), "v"(b), "v"(c));
  return d;
}

// ---------------- geometry ----------------
__global__ __launch_bounds__(256)
void egeom_k(const float* __restrict__ R, const int* __restrict__ ei,
             const int* __restrict__ ej, float* __restrict__ Dij, float* __restrict__ rbf){
  int e = blockIdx.x*256 + threadIdx.x;
  int i = ei[e], j = ej[e];
  float dx = R[i*3+0]-R[j*3+0];
  float dy = R[i*3+1]-R[j*3+1];
  float dz = R[i*3+2]-R[j*3+2];
  float d2 = dx*dx+dy*dy+dz*dz;
  float D = sqrtf(fmaxf(d2, 0.f));
  Dij[e] = D;
  float d = fmaxf(D, 1e-6f);
  float s = PI_F*d*0.2f;
  float sn, cs; sincosf(s, &sn, &cs);
  float invd = SQ25/d;
  float sprev = 0.f, scur = sn;
  #pragma unroll
  for (int q=0;q<6;q++){
    rbf[e*6+q] = scur*invd;
    float nx = 2.f*cs*scur - sprev; sprev = scur; scur = nx;
  }
}

__global__ __launch_bounds__(256)
void tgeom_k(const float* __restrict__ R, const int* __restrict__ t3i,
             const int* __restrict__ t3j, const int* __restrict__ t3k,
             const int* __restrict__ texp, const float* __restrict__ Dij,
             float* __restrict__ angrad){
  int w = blockIdx.x*256 + threadIdx.x;
  int ia = t3i[w], ja = t3j[w], ka = t3k[w];
  float xi = R[ia*3+0], yi = R[ia*3+1], zi = R[ia*3+2];
  float r1x = R[ja*3+0]-xi, r1y = R[ja*3+1]-yi, r1z = R[ja*3+2]-zi;
  float r2x = R[ka*3+0]-xi, r2y = R[ka*3+1]-yi, r2z = R[ka*3+2]-zi;
  float dt = r1x*r2x + r1y*r2y + r1z*r2z;
  float cx = r1y*r2z - r1z*r2y;
  float cy = r1z*r2x - r1x*r2z;
  float cz = r1x*r2y - r1y*r2x;
  float yv = sqrtf(cx*cx + cy*cy + cz*cz);
  float h = sqrtf(dt*dt + yv*yv);
  float c1 = (h > 0.f) ? dt/h : 1.f;   // cos(atan2(y,x)); atan2(0,0)=0 -> cos=1
  angrad[0*NTc + w] = 1.f;
  angrad[1*NTc + w] = c1;
  float cprev = 1.f, ccur = c1;
  #pragma unroll
  for (int l=2;l<7;l++){
    float nx = 2.f*c1*ccur - cprev; cprev = ccur; ccur = nx;
    angrad[l*NTc + w] = nx;
  }
  float d = fmaxf(Dij[texp[w]], 1e-6f);
  float s = PI_F*d*0.2f;
  float sn, cs; sincosf(s, &sn, &cs);
  float invd = 1.f/d;
  float sprev = 0.f, scur = sn;
  #pragma unroll
  for (int q=0;q<7;q++){
    angrad[(7+q)*NTc + w] = scur*invd;
    float nx = 2.f*cs*scur - sprev; sprev = scur; scur = nx;
  }
}

// ---------------- weight prep (fp32 -> bf16, transpose to [N,K]) ----------------
__global__ __launch_bounds__(256)
void prep_transpose(const float* __restrict__ Wemb, const float* __restrict__ Wji,
                    const float* __restrict__ Wkj, const float* __restrict__ Wfin,
                    unsigned short* __restrict__ dW12, unsigned short* __restrict__ dWji,
                    unsigned short* __restrict__ dWkj, unsigned short* __restrict__ dWfin){
  int y = blockIdx.y;
  int x = blockIdx.x*256 + threadIdx.x;
  if (y == 0){
    if (x < 32768){
      int n = x >> 8, k = x & 255;
      dW12[x] = f2bf(Wemb[k*128 + n]);
    }
  } else {
    if (x < 16384){
      int n = x >> 7, k = x & 127;
      const float* s; unsigned short* d;
      if (y <= 7)      { s = Wji  + (y-1)*16384;  d = dWji  + (y-1)*16384; }
      else if (y <= 14){ s = Wkj  + (y-8)*16384;  d = dWkj  + (y-8)*16384; }
      else             { s = Wfin + (y-15)*16384; d = dWfin + (y-15)*16384; }
      d[x] = f2bf(s[k*128 + n]);
    }
  }
}

__global__ __launch_bounds__(256)
void prep_wbil(const float* __restrict__ Wbil, unsigned short* __restrict__ dst){
  int x = blockIdx.x*256 + threadIdx.x;
  if (x < 7*131072){
    int i = x >> 17; int rem = x & 131071;
    int o = rem >> 10; int lj = rem & 1023;
    int l = lj >> 7; int j = lj & 127;
    dst[x] = f2bf(Wbil[(size_t)i*131072 + (size_t)(j*8+l)*128 + o]);
  }
}

__global__ __launch_bounds__(256)
void prep_emb(const float* __restrict__ emb, unsigned short* __restrict__ d){
  int x = blockIdx.x*256 + threadIdx.x;
  if (x < 95*128) d[x] = f2bf(emb[x]);
}

// ---------------- counting sort ----------------
__global__ __launch_bounds__(256)
void hist_k(const int* __restrict__ ids, int n, int* __restrict__ hist){
  int stride = gridDim.x*blockDim.x;
  for (int x = blockIdx.x*blockDim.x + threadIdx.x; x < n; x += stride)
    atomicAdd(&hist[ids[x]], 1);
}

__global__ __launch_bounds__(1024)
void scan_k(const int* __restrict__ hist, int* __restrict__ offs, int nbins){
  __shared__ int part[1024];
  int tid = threadIdx.x;
  int per = nbins >> 10;
  int base = tid*per;
  int s = 0;
  for (int q=0;q<per;q++) s += hist[base+q];
  part[tid] = s;
  __syncthreads();
  for (int d=1; d<1024; d<<=1){
    int v = (tid>=d) ? part[tid-d] : 0;
    __syncthreads();
    part[tid] += v;
    __syncthreads();
  }
  int run = (tid>0) ? part[tid-1] : 0;
  for (int q=0;q<per;q++){ offs[base+q] = run; run += hist[base+q]; }
  if (tid==1023) offs[nbins] = part[1023];
}

__global__ __launch_bounds__(256)
void scatter_k(const int* __restrict__ ids, int n, const int* __restrict__ offs,
               int* __restrict__ cursor, int* __restrict__ perm){
  int stride = gridDim.x*blockDim.x;
  for (int x = blockIdx.x*blockDim.x + threadIdx.x; x < n; x += stride){
    int b = ids[x];
    int pos = offs[b] + atomicAdd(&cursor[b], 1);
    perm[pos] = x;
  }
}

// ---------------- sb = sbf @ Wsbf[i]  [T,8] ----------------
__global__ __launch_bounds__(256)
void sb_k(const float* __restrict__ angrad, const float* __restrict__ Wsbf,
          float* __restrict__ sb){
  __shared__ float Ws[392];
  for (int x = threadIdx.x; x < 392; x += 256) Ws[x] = Wsbf[x];
  __syncthreads();
  int w = blockIdx.x*256 + threadIdx.x;
  float ca[7], rd[7];
  #pragma unroll
  for (int q=0;q<7;q++){ ca[q] = angrad[q*NTc + w]; rd[q] = angrad[(7+q)*NTc + w]; }
  float o[8] = {0,0,0,0,0,0,0,0};
  #pragma unroll
  for (int a=0;a<7;a++){
    #pragma unroll
    for (int r=0;r<7;r++){
      float pr = ca[a]*rd[r];
      const float* wp = &Ws[(a*7+r)*8];
      #pragma unroll
      for (int l=0;l<8;l++) o[l] += pr*wp[l];
    }
  }
  #pragma unroll
  for (int l=0;l<8;l++) sb[(size_t)w*8 + l] = o[l];
}

// ---------------- G[r,l,j] = sum_{w in r} sb[w,l]*xkj[exp[w],j]  (wave per edge) ----------------
__global__ __launch_bounds__(256)
void gbuild_k(int c0, const int* __restrict__ tperm, const int* __restrict__ toffs,
              const int* __restrict__ texp, const float* __restrict__ sb,
              const unsigned short* __restrict__ xkj, unsigned short* __restrict__ G){
  int lane = threadIdx.x & 63;
  int wv = threadIdx.x >> 6;
  int r = c0 + blockIdx.x*4 + wv;
  float acc[8][2] = {};
  int s = toffs[r], e_ = toffs[r+1];
  for (int t = s; t < e_; t++){
    int wt = tperm[t];
    int e = texp[wt];
    unsigned xv = *(const unsigned*)&xkj[(size_t)e*128 + lane*2];
    float x0 = bf2f((unsigned short)(xv & 0xffffu));
    float x1 = bf2f((unsigned short)(xv >> 16));
    const float* sp = sb + (size_t)wt*8;
    #pragma unroll
    for (int l=0;l<8;l++){ float sl = sp[l]; acc[l][0] += sl*x0; acc[l][1] += sl*x1; }
  }
  size_t gb = (size_t)(r - c0)*1024 + lane*2;
  #pragma unroll
  for (int l=0;l<8;l++){
    unsigned pv = (unsigned)f2bf(acc[l][0]) | ((unsigned)f2bf(acc[l][1]) << 16);
    *(unsigned*)&G[gb + l*128] = pv;
  }
}

// ---------------- generic MFMA GEMM: C[M,128] = A[M,K] @ Bt[128,K]^T ----------------
// MODE 0: A direct bf16 [rows, K] (chunk-local via arow0). MODE 1: embedding gather.
// EPI 0: m0 = swish(acc + b + rbf@Wemb_tail) -> outF(m f32) + outB(m bf16)
// EPI 1: swish(acc + bias) -> outB
// EPI 2: swish(acc + bias) * (rbf @ W6) -> outB
// EPI 3: acc + xji -> outB (Afin)
// EPI 4: m += swish(acc + bias) -> outF(m) + outB(m bf16)
template<int MODE, int EPI>
__global__ __launch_bounds__(256)
void gemm_k(const unsigned short* __restrict__ A, const unsigned short* __restrict__ Bt,
            int K, int rowoff, int arow0,
            const int* __restrict__ gi, const int* __restrict__ gj, const int* __restrict__ Zr,
            const float* __restrict__ rbfp, const float* __restrict__ W6,
            const float* __restrict__ bias, const float* minp,
            const unsigned short* __restrict__ xjip,
            float* outF, unsigned short* outB){
  __shared__ __align__(16) unsigned short As[128*72];
  __shared__ __align__(16) unsigned short Bs[128*72];
  const int tid = threadIdx.x;
  const int lane = tid & 63;
  const int wid = tid >> 6;
  const int wr = wid >> 1, wc = wid & 1;
  const int rowbase = rowoff + blockIdx.x*128;
  floatx4 acc[4][4];
  #pragma unroll
  for (int i=0;i<4;i++)
    #pragma unroll
    for (int j=0;j<4;j++) acc[i][j] = (floatx4){0.f,0.f,0.f,0.f};

  for (int k0 = 0; k0 < K; k0 += 64){
    shortx8 ra[4], rb[4];
    #pragma unroll
    for (int q=0;q<4;q++){
      int c = q*256 + tid;
      int row = c >> 3;
      int ko = (c & 7) << 3;
      const unsigned short* asrc;
      if (MODE == 0){
        asrc = A + (size_t)(rowbase - arow0 + row)*K + k0 + ko;
      } else {
        int grow = rowbase + row;
        int kg = k0 + ko;
        int atom = (kg < 128) ? gi[grow] : gj[grow];
        asrc = A + (size_t)Zr[atom]*128 + (kg & 127);
      }
      ra[q] = *(const shortx8*)asrc;
      rb[q] = *(const shortx8*)(Bt + (size_t)row*K + k0 + ko);
    }
    __syncthreads();
    #pragma unroll
    for (int q=0;q<4;q++){
      int c = q*256 + tid;
      int row = c >> 3;
      int ko = (c & 7) << 3;
      *(shortx8*)&As[row*72 + ko] = ra[q];
      *(shortx8*)&Bs[row*72 + ko] = rb[q];
    }
    __syncthreads();
    #pragma unroll
    for (int kk=0; kk<2; kk++){
      shortx8 af[4], bfr[4];
      #pragma unroll
      for (int mi=0;mi<4;mi++)
        af[mi] = *(const shortx8*)&As[(wr*64 + mi*16 + (lane&15))*72 + kk*32 + ((lane>>4)<<3)];
      #pragma unroll
      for (int ni=0;ni<4;ni++)
        bfr[ni] = *(const shortx8*)&Bs[(wc*64 + ni*16 + (lane&15))*72 + kk*32 + ((lane>>4)<<3)];
      #pragma unroll
      for (int mi=0;mi<4;mi++)
        #pragma unroll
        for (int ni=0;ni<4;ni++)
          acc[mi][ni] = mfma16x16x32bf(af[mi], bfr[ni], acc[mi][ni]);
    }
  }
  asm volatile("s_nop 7\ns_nop 7\ns_nop 7");   // MFMA->VALU hazard guard (inline asm bypasses compiler)

  #pragma unroll
  for (int mi=0;mi<4;mi++){
    #pragma unroll
    for (int j=0;j<4;j++){
      int row = wr*64 + mi*16 + ((lane>>4)<<2) + j;   // C/D: row=(lane>>4)*4+reg  [m89]
      int grow = rowbase + row;
      float rb6[6];
      if (EPI==0 || EPI==2){
        #pragma unroll
        for (int q=0;q<6;q++) rb6[q] = rbfp[grow*6+q];
      }
      #pragma unroll
      for (int ni=0;ni<4;ni++){
        int col = wc*64 + ni*16 + (lane&15);           // C/D: col=lane&15
        float v = acc[mi][ni][j];
        size_t oidx = (size_t)grow*128 + col;
        if (EPI==0){
          float e = bias[col];
          #pragma unroll
          for (int q=0;q<6;q++) e += rb6[q]*W6[q*128+col];
          v = swishf(v + e);
          outF[oidx] = v;
          outB[oidx] = f2bf(v);
        } else if (EPI==1){
          v = swishf(v + bias[col]);
          outB[oidx] = f2bf(v);
        } else if (EPI==2){
          float rp = 0.f;
          #pragma unroll
          for (int q=0;q<6;q++) rp += rb6[q]*W6[q*128+col];
          v = swishf(v + bias[col]) * rp;
          outB[oidx] = f2bf(v);
        } else if (EPI==3){
          v += bf2f(xjip[oidx]);
          outB[oidx] = f2bf(v);
        } else {
          float nm = minp[oidx] + swishf(v + bias[col]);
          outF[oidx] = nm;
          outB[oidx] = f2bf(nm);
        }
      }
    }
  }
}

// ---------------- out_layer: wave per atom ----------------
__global__ __launch_bounds__(256)
void out_layer_k(const int* __restrict__ eperm, const int* __restrict__ eoffs,
                 const unsigned short* __restrict__ mbf, const float* __restrict__ rbf,
                 const float* __restrict__ Wrbf, const float* __restrict__ W1,
                 const float* __restrict__ b1, const float* __restrict__ W2,
                 const int* __restrict__ bseg, float* __restrict__ out){
  __shared__ float ta_lds[4][128];
  int lane = threadIdx.x & 63;
  int wv = threadIdx.x >> 6;
  int a = blockIdx.x*4 + wv;
  int f0 = lane*2;
  float wr0[6], wr1[6];
  #pragma unroll
  for (int q=0;q<6;q++){ wr0[q] = Wrbf[q*128+f0]; wr1[q] = Wrbf[q*128+f0+1]; }
  float ta0 = 0.f, ta1 = 0.f;
  int s = eoffs[a], e_ = eoffs[a+1];
  for (int t = s; t < e_; t++){
    int e = eperm[t];
    unsigned mv = *(const unsigned*)&mbf[(size_t)e*128 + f0];
    float r0 = rbf[e*6+0], r1 = rbf[e*6+1], r2 = rbf[e*6+2];
    float r3 = rbf[e*6+3], r4 = rbf[e*6+4], r5 = rbf[e*6+5];
    float rp0 = r0*wr0[0]+r1*wr0[1]+r2*wr0[2]+r3*wr0[3]+r4*wr0[4]+r5*wr0[5];
    float rp1 = r0*wr1[0]+r1*wr1[1]+r2*wr1[2]+r3*wr1[3]+r4*wr1[4]+r5*wr1[5];
    ta0 += bf2f((unsigned short)(mv & 0xffffu))*rp0;
    ta1 += bf2f((unsigned short)(mv >> 16))*rp1;
  }
  ta_lds[wv][f0]   = ta0;
  ta_lds[wv][f0+1] = ta1;
  // wave-coherent LDS (no cross-wave sharing); compiler inserts lgkmcnt waits
  float p = 0.f;
  #pragma unroll
  for (int h=0; h<2; h++){
    int n = lane + h*64;
    float o = b1[n];
    for (int f=0; f<128; f++) o += ta_lds[wv][f]*W1[f*128+n];
    p += swishf(o)*W2[n];
  }
  #pragma unroll
  for (int off=32; off; off>>=1) p += __shfl_down(p, off);
  if (lane == 0) atomicAdd(&out[bseg[a]], p);
}

// ---------------- launch ----------------
extern "C" void kernel_launch(void* const* d_in, const int* in_sizes, int n_in,
                              void* d_out, int out_size, void* d_ws, size_t ws_size,
                              hipStream_t stream){
  const int*   Z    = (const int*)d_in[0];
  const float* R    = (const float*)d_in[1];
  const int*   bseg = (const int*)d_in[2];
  const int*   ei   = (const int*)d_in[3];
  const int*   ej   = (const int*)d_in[4];
  const int*   texp = (const int*)d_in[5];
  const int*   tred = (const int*)d_in[6];
  const int*   t3i  = (const int*)d_in[7];
  const int*   t3j  = (const int*)d_in[8];
  const int*   t3k  = (const int*)d_in[9];
  const float* emb  = (const float*)d_in[10];
  const float* Wemb = (const float*)d_in[11];
  const float* bemb = (const float*)d_in[12];
  const float* oWr  = (const float*)d_in[13];
  const float* oW1  = (const float*)d_in[14];
  const float* ob1  = (const float*)d_in[15];
  const float* oW2  = (const float*)d_in[16];
  const float* iWr  = (const float*)d_in[17];
  const float* iWs  = (const float*)d_in[18];
  const float* iWkj = (const float*)d_in[19];
  const float* ibkj = (const float*)d_in[20];
  const float* iWji = (const float*)d_in[21];
  const float* ibji = (const float*)d_in[22];
  const float* iWb  = (const float*)d_in[23];
  const float* iWf  = (const float*)d_in[24];
  const float* ibf  = (const float*)d_in[25];
  float* out = (float*)d_out;

  char* p = (char*)d_ws;
  auto alloc = [&](size_t bytes)->char*{ char* r = p; p += (bytes + 255) & ~(size_t)255; return r; };
  float* Dij    = (float*)alloc((size_t)NEc*4);
  float* rbf    = (float*)alloc((size_t)NEc*6*4);
  float* angrad = (float*)alloc((size_t)14*NTc*4);
  float* sball  = (float*)alloc((size_t)NTc*8*4);
  float* m      = (float*)alloc((size_t)NEc*128*4);
  unsigned short* mbf  = (unsigned short*)alloc((size_t)NEc*128*2);
  unsigned short* xji  = (unsigned short*)alloc((size_t)NEc*128*2);
  unsigned short* xkj  = (unsigned short*)alloc((size_t)NEc*128*2);
  unsigned short* afin = (unsigned short*)alloc((size_t)NEc*128*2);
  int* thist = (int*)alloc((size_t)NEc*4);
  int* toffs = (int*)alloc((size_t)(NEc+1)*4);
  int* tperm = (int*)alloc((size_t)NTc*4);
  int* ehist = (int*)alloc((size_t)NAc*4);
  int* eoffs = (int*)alloc((size_t)(NAc+1)*4);
  int* eperm = (int*)alloc((size_t)NEc*4);
  unsigned short* embbf = (unsigned short*)alloc((size_t)95*128*2);
  unsigned short* W12et = (unsigned short*)alloc((size_t)128*256*2);
  unsigned short* Wjit  = (unsigned short*)alloc((size_t)7*16384*2);
  unsigned short* Wkjt  = (unsigned short*)alloc((size_t)7*16384*2);
  unsigned short* Wfint = (unsigned short*)alloc((size_t)7*16384*2);
  unsigned short* Wbilt = (unsigned short*)alloc((size_t)7*131072*2);
  size_t fixed = (size_t)(p - (char*)d_ws);

  // choose G chunking to fit workspace
  int nch = 1;
  while (nch < 8 && fixed + ((size_t)NEc/nch)*1024*2 > ws_size) nch <<= 1;
  int ECH = NEc / nch;
  unsigned short* Gbuf = (unsigned short*)alloc((size_t)ECH*1024*2);

  hipMemsetAsync(d_out, 0, 64*sizeof(float), stream);
  hipMemsetAsync(thist, 0, (size_t)NEc*4, stream);
  hipMemsetAsync(ehist, 0, (size_t)NAc*4, stream);

  prep_transpose<<<dim3(128,22),256,0,stream>>>(Wemb, iWji, iWkj, iWf, W12et, Wjit, Wkjt, Wfint);
  prep_wbil<<<3584,256,0,stream>>>(iWb, Wbilt);
  prep_emb<<<48,256,0,stream>>>(emb, embbf);
  egeom_k<<<NEc/256,256,0,stream>>>(R, ei, ej, Dij, rbf);
  tgeom_k<<<NTc/256,256,0,stream>>>(R, t3i, t3j, t3k, texp, Dij, angrad);

  // triplet sort by id_reduce_ji
  hist_k<<<512,256,0,stream>>>(tred, NTc, thist);
  scan_k<<<1,1024,0,stream>>>(thist, toffs, NEc);
  hipMemsetAsync(thist, 0, (size_t)NEc*4, stream);
  scatter_k<<<512,256,0,stream>>>(tred, NTc, toffs, thist, tperm);
  // edge sort by idnb_i
  hist_k<<<256,256,0,stream>>>(ei, NEc, ehist);
  scan_k<<<1,1024,0,stream>>>(ehist, eoffs, NAc);
  hipMemsetAsync(ehist, 0, (size_t)NAc*4, stream);
  scatter_k<<<256,256,0,stream>>>(ei, NEc, eoffs, ehist, eperm);

  // m0 = swish([h_i,h_j,rbf] @ W_emb + b)
  gemm_k<1,0><<<NEc/128,256,0,stream>>>(embbf, W12et, 256, 0, 0, ei, ej, Z,
                                        rbf, Wemb + 256*128, bemb, nullptr, nullptr, m, mbf);
  out_layer_k<<<NAc/4,256,0,stream>>>(eperm, eoffs, mbf, rbf,
                                      oWr, oW1, ob1, oW2, bseg, out);

  for (int i=0;i<7;i++){
    sb_k<<<NTc/256,256,0,stream>>>(angrad, iWs + i*392, sball);
    gemm_k<0,1><<<NEc/128,256,0,stream>>>(mbf, Wjit + i*16384, 128, 0, 0,
        nullptr, nullptr, nullptr, nullptr, nullptr, ibji + i*128, nullptr, nullptr, nullptr, xji);
    gemm_k<0,2><<<NEc/128,256,0,stream>>>(mbf, Wkjt + i*16384, 128, 0, 0,
        nullptr, nullptr, nullptr, rbf, iWr + i*768, ibkj + i*128, nullptr, nullptr, nullptr, xkj);
    for (int c=0;c<nch;c++){
      int c0 = c*ECH;
      gbuild_k<<<ECH/4,256,0,stream>>>(c0, tperm, toffs, texp, sball, xkj, Gbuf);
      gemm_k<0,3><<<ECH/128,256,0,stream>>>(Gbuf, Wbilt + i*131072, 1024, c0, c0,
          nullptr, nullptr, nullptr, nullptr, nullptr, nullptr, nullptr, xji, nullptr, afin);
    }
    gemm_k<0,4><<<NEc/128,256,0,stream>>>(afin, Wfint + i*16384, 128, 0, 0,
        nullptr, nullptr, nullptr, nullptr, nullptr, ibf + i*128, m, nullptr, m, mbf);
    out_layer_k<<<NAc/4,256,0,stream>>>(eperm, eoffs, mbf, rbf,
        oWr + (i+1)*768, oW1 + (i+1)*16384, ob1 + (i+1)*128, oW2 + (i+1)*128, bseg, out);
  }
  (void)in_sizes; (void)n_in; (void)out_size;
}